// Round 6
// baseline (154.439 us; speedup 1.0000x reference)
//
#include <hip/hip_runtime.h>

// Problem constants (SubOut_60206851555968): B=8, U=E=1024, D=P=256, fp32 in/out.
#define BDIM 8
#define UDIM 1024
#define EDIM 1024
#define DDIM 256
#define PDIM 256

typedef __attribute__((ext_vector_type(8))) short bf16x8;   // 8 bf16 = 4 VGPRs
typedef __attribute__((ext_vector_type(4))) float f32x4;    // clang ext_vector: legal in asm "v"

__device__ __forceinline__ short f2bf(float x) {
    unsigned u = __float_as_uint(x);
    unsigned r = (u + 0x7FFFu + ((u >> 16) & 1u)) >> 16;   // RNE
    return (short)r;
}

// Async global->LDS DMA, 16B per lane. LDS dest = wave-uniform base + lane*16;
// global src is per-lane (swizzled LDS layouts = pre-swizzle the SOURCE).
__device__ __forceinline__ void dma16(const void* g, void* lds) {
    __builtin_amdgcn_global_load_lds(
        (const __attribute__((address_space(1))) unsigned*)g,
        (__attribute__((address_space(3))) unsigned*)lds, 16, 0, 0);
}

// Keep-alive (ext_vector/scalar operands ONLY — HIP float4 is a class type).
#define KEEP(x) asm volatile("" :: "v"(x))

// ---------------------------------------------------------------------------
// prep: wT[n][k] = bf16(w[k][n]); zero sums + out.  (unchanged)
// ---------------------------------------------------------------------------
__global__ __launch_bounds__(256) void prep_kernel(
    const float* __restrict__ w, ushort* __restrict__ wT,
    float* __restrict__ sums /* row_sums||col_sums, 16384 */,
    float* __restrict__ out, int out_size)
{
    int k  = threadIdx.x;          // D index
    int n0 = blockIdx.x * 4;       // P index base
    f32x4 wv = *(const f32x4*)(w + (size_t)k * PDIM + n0);
    wT[(size_t)(n0 + 0) * DDIM + k] = (ushort)f2bf(wv[0]);
    wT[(size_t)(n0 + 1) * DDIM + k] = (ushort)f2bf(wv[1]);
    wT[(size_t)(n0 + 2) * DDIM + k] = (ushort)f2bf(wv[2]);
    wT[(size_t)(n0 + 3) * DDIM + k] = (ushort)f2bf(wv[3]);
    int g = blockIdx.x * 256 + k;
    sums[g] = 0.f;                              // exactly 16384
    if (g < out_size) out[g] = 0.f;
}

// ---------------------------------------------------------------------------
// proj v4b: u_p/e_p = bf16(enc @ w + bias), MFMA 16x16x32 bf16.  (unchanged)
// ---------------------------------------------------------------------------
__global__ __launch_bounds__(256) void proj_kernel(
    const float* __restrict__ u_enc, const float* __restrict__ e_enc,
    const ushort* __restrict__ wT, const float* __restrict__ bias,
    ushort* __restrict__ u_p, ushort* __restrict__ e_p)
{
    __shared__ ushort lds_b[64 * 256];   // 32 KB, swizzled: byte = rl*512 + (cb ^ ((rl&7)<<4))

    int bid  = blockIdx.x;                 // 0..1023
    int lin  = (bid & 7) * 128 + (bid >> 3);
    int row0 = (lin >> 2) * 64;
    int col0 = (lin & 3) * 64;

    const float* A; ushort* C;
    if (row0 < BDIM * UDIM) { A = u_enc; C = u_p; }
    else                    { A = e_enc; C = e_p; row0 -= BDIM * UDIM; }

    int tid  = threadIdx.x;
    int wave = tid >> 6, lane = tid & 63;
    int m = lane & 15, quad = lane >> 4;

    // ---- stage wT rows [col0, col0+64) into LDS, swizzled source ----
    {
        int rl_base = wave * 16;
        int lr = lane >> 5;            // 0/1
        int cb = (lane & 31) * 16;     // 0..496
        #pragma unroll
        for (int j = 0; j < 8; ++j) {
            int rl = rl_base + 2 * j + lr;
            const ushort* src = wT + (size_t)(col0 + rl) * DDIM + ((cb ^ ((rl & 7) << 4)) >> 1);
            dma16(src, &lds_b[(size_t)(rl_base + 2 * j) * DDIM]);
        }
    }

    // ---- A strip: 16 x f32x4 batched into registers, KEEP-pinned ----
    const float* aptr = A + (size_t)(row0 + wave * 16 + m) * DDIM + quad * 8;
    f32x4 a[16];
    #pragma unroll
    for (int i = 0; i < 8; ++i) {
        a[2 * i]     = *(const f32x4*)(aptr + 32 * i);
        a[2 * i + 1] = *(const f32x4*)(aptr + 32 * i + 4);
    }
    #pragma unroll
    for (int i = 0; i < 16; ++i) KEEP(a[i]);

    asm volatile("s_waitcnt vmcnt(0)" ::: "memory");
    __syncthreads();

    int rowmask = (m & 7) << 4;        // swizzle term: B row = nt*16 + m -> row&7 = m&7
    f32x4 acc[4] = {};
    #pragma unroll
    for (int i = 0; i < 8; ++i) {
        bf16x8 af;
        af[0] = f2bf(a[2*i][0]);   af[1] = f2bf(a[2*i][1]);
        af[2] = f2bf(a[2*i][2]);   af[3] = f2bf(a[2*i][3]);
        af[4] = f2bf(a[2*i+1][0]); af[5] = f2bf(a[2*i+1][1]);
        af[6] = f2bf(a[2*i+1][2]); af[7] = f2bf(a[2*i+1][3]);
        #pragma unroll
        for (int nt = 0; nt < 4; ++nt) {
            int elem = (nt * 16 + m) * DDIM + (((quad * 16 + 64 * i) ^ rowmask) >> 1);
            bf16x8 bfr = *(const bf16x8*)(lds_b + elem);
            acc[nt] = __builtin_amdgcn_mfma_f32_16x16x32_bf16(af, bfr, acc[nt], 0, 0, 0);
        }
    }

    // C/D layout: col = lane&15, row = quad*4 + reg.
    #pragma unroll
    for (int nt = 0; nt < 4; ++nt) {
        int col = col0 + nt * 16 + m;
        float bv = bias[col];
        #pragma unroll
        for (int r = 0; r < 4; ++r) {
            int row = row0 + wave * 16 + quad * 4 + r;
            C[(size_t)row * PDIM + col] = (ushort)f2bf(acc[nt][r] + bv);
        }
    }
}

// ---------------------------------------------------------------------------
// fused v7: counted-vmcnt double-buffered pipeline (T3/T4).
// v6 was single-shot stage->drain(vmcnt 0)->compute: memory idle during every
// compute/epilogue window, full cold-drain latency per block. v7: each block
// owns (b, u-strip, e-group) and loops 4 consecutive e-tiles with 2x LDS
// buffers. Per iter: raw s_barrier (readers of victim buf done) -> issue next
// tile's 16 DMAs/wave -> s_waitcnt vmcnt(16) (counted: current tile ready,
// prefetch stays in flight) -> s_barrier -> MFMA+gate from LDS. Raw
// s_barrier everywhere (__syncthreads would re-insert the vmcnt(0) drain).
// af (u-strip) loaded once per block (was per tile); rsum accumulates in
// regs across tiles (4x fewer row atomics). LDS 129KB -> 1 block/CU.
// vmcnt ledger/wave: prologue 16 (t0) + 8 (af); iter t<3 issues 16 more;
// vmcnt(16) retires everything except the newest 16; t=3: vmcnt(0).
// ---------------------------------------------------------------------------
__global__ __launch_bounds__(256) void fused_kernel(
    const ushort* __restrict__ u_p, const ushort* __restrict__ e_p,
    const float* __restrict__ pair_enc, const float* __restrict__ ue_mask,
    const float* __restrict__ bpp_w_p, const float* __restrict__ bpp_b_p,
    float* __restrict__ row_sums, float* __restrict__ col_sums)
{
    __shared__ ushort lds_e[2][64 * 256];   // 2 x 32 KB, swizzled
    __shared__ float lds_pair[2][64][64];   // 2 x 16 KB, linear
    __shared__ float lds_mask[2][64][64];   // 2 x 16 KB, linear
    __shared__ float colred[4][64];         // 1 KB

    int bid  = blockIdx.x;          // 0..511
    int b    = bid & 7;             // batch <-> XCD
    int tile = bid >> 3;            // 0..63
    int iu   = tile >> 2;           // 0..15
    int eg   = tile & 3;            // 0..3
    int u0   = iu * 64;
    int e0g  = eg * 256;            // this block covers e in [e0g, e0g+256)

    int tid  = threadIdx.x;
    int wave = tid >> 6, lane = tid & 63;
    int m = lane & 15, quad = lane >> 4;

    const float* pm = pair_enc + (size_t)b * UDIM * EDIM;
    const float* mm = ue_mask  + (size_t)b * UDIM * EDIM;
    const ushort* eb = e_p + (size_t)b * EDIM * PDIM;

    // stage one e-tile + pair/mask tile into buffer `buf` (16 dma16 per wave)
    int srl  = wave * 16 + (lane >> 5);      // e-stage local row (+2j)
    int scb  = (lane & 31) * 16;             // e-stage byte-in-row
    int plr  = lane >> 4;                    // pair/mask row-in-group
    int plc  = (lane & 15) * 4;              // pair/mask float col
    #define STAGE_TILE(t, buf) {                                               \
        int e0 = e0g + (t) * 64;                                               \
        _Pragma("unroll")                                                      \
        for (int j = 0; j < 8; ++j) {                                          \
            int rl = srl + 2 * j;                                              \
            const ushort* src = eb + (size_t)(e0 + rl) * PDIM                  \
                                + ((scb ^ ((rl & 7) << 4)) >> 1);              \
            dma16(src, &lds_e[buf][(size_t)(wave * 16 + 2 * j) * PDIM]);       \
        }                                                                      \
        _Pragma("unroll")                                                      \
        for (int j = 0; j < 4; ++j) {                                          \
            int r0 = wave * 16 + j * 4;                                        \
            size_t goff = (size_t)(u0 + r0 + plr) * EDIM + e0 + plc;           \
            dma16(pm + goff, &lds_pair[buf][r0][0]);                           \
            dma16(mm + goff, &lds_mask[buf][r0][0]);                           \
        }                                                                      \
    }

    // ---- prologue: stage tile 0, then af (u-strip, reused by all 4 tiles) ----
    STAGE_TILE(0, 0);

    const ushort* Au = u_p + (size_t)b * UDIM * PDIM + (size_t)(u0 + wave * 16 + m) * PDIM + quad * 8;
    bf16x8 af[8];
    #pragma unroll
    for (int i = 0; i < 8; ++i) af[i] = *(const bf16x8*)(Au + 32 * i);
    #pragma unroll
    for (int i = 0; i < 8; ++i) KEEP(af[i]);

    float bw = bpp_w_p[0], bb = bpp_b_p[0];
    int rowmask = (m & 7) << 4;

    float rsum[4] = {0.f, 0.f, 0.f, 0.f};   // accumulates across all 4 e-tiles

    #pragma unroll
    for (int t = 0; t < 4; ++t) {
        int buf = t & 1;

        // all waves done reading buf^1 (iter t-1's compute) -> safe to overwrite
        __builtin_amdgcn_s_barrier();
        if (t < 3) STAGE_TILE(t + 1, buf ^ 1);
        __builtin_amdgcn_sched_barrier(0);
        if (t < 3) asm volatile("s_waitcnt vmcnt(16)" ::: "memory");
        else       asm volatile("s_waitcnt vmcnt(0)"  ::: "memory");
        __builtin_amdgcn_sched_barrier(0);
        __builtin_amdgcn_s_barrier();       // all waves' tile-t data in LDS

        // ---- MFMA: B frags from swizzled LDS e-tile ----
        f32x4 acc[4] = {};
        #pragma unroll
        for (int i = 0; i < 8; ++i) {
            #pragma unroll
            for (int nt = 0; nt < 4; ++nt) {
                int elem = (nt * 16 + m) * PDIM + (((quad * 16 + 64 * i) ^ rowmask) >> 1);
                bf16x8 bfr = *(const bf16x8*)(&lds_e[buf][0] + elem);
                acc[nt] = __builtin_amdgcn_mfma_f32_16x16x32_bf16(af[i], bfr, acc[nt], 0, 0, 0);
            }
        }

        // ---- gate + partial sums from LDS ----
        float csum[4] = {0.f, 0.f, 0.f, 0.f};
        #pragma unroll
        for (int r = 0; r < 4; ++r) {
            int row = wave * 16 + quad * 4 + r;
            #pragma unroll
            for (int nt = 0; nt < 4; ++nt) {
                int col = nt * 16 + m;
                float mv = lds_mask[buf][row][col];
                float pv = lds_pair[buf][row][col];
                float arg = bw * pv + bb + mv * acc[nt][r];
                float s = mv / (1.f + __expf(-arg));
                rsum[r]  += s;
                csum[nt] += s;
            }
        }

        // ---- col sums: quad-reduce, cross-wave via colred. lgkmcnt-only
        // barrier (no vmcnt drain -> prefetch stays in flight). ----
        #pragma unroll
        for (int nt = 0; nt < 4; ++nt) {
            float v = csum[nt];
            v += __shfl_xor(v, 16); v += __shfl_xor(v, 32);
            if (quad == 0) colred[wave][nt * 16 + m] = v;
        }
        asm volatile("s_waitcnt lgkmcnt(0)" ::: "memory");
        __builtin_amdgcn_s_barrier();
        if (tid < 64) {
            float v = colred[0][tid] + colred[1][tid] + colred[2][tid] + colred[3][tid];
            atomicAdd(&col_sums[(size_t)b * EDIM + e0g + t * 64 + tid], v);
        }
        // colred rewrite (iter t+1 epilogue) is ordered after this read by the
        // two barriers at the top of iter t+1.
    }

    // ---- row sums once: reduce across the 16 lanes of each quad ----
    #pragma unroll
    for (int r = 0; r < 4; ++r) {
        float v = rsum[r];
        v += __shfl_xor(v, 1); v += __shfl_xor(v, 2);
        v += __shfl_xor(v, 4); v += __shfl_xor(v, 8);
        if (m == 0)
            atomicAdd(&row_sums[(size_t)b * UDIM + u0 + wave * 16 + quad * 4 + r], v);
    }
    #undef STAGE_TILE
}

// ---------------------------------------------------------------------------
// finish v3b: out[b,0:256] = row_sums[b,:] @ u_enc[b]; out[b,256:512] = col_sums @ e_enc.
// (unchanged)
// ---------------------------------------------------------------------------
__global__ __launch_bounds__(256) void finish_kernel(
    const float* __restrict__ u_enc, const float* __restrict__ e_enc,
    const float* __restrict__ row_sums, const float* __restrict__ col_sums,
    float* __restrict__ out)
{
    int b = blockIdx.x;
    int half = blockIdx.y;
    int chunk = blockIdx.z;        // 0..31
    int d = threadIdx.x;

    const float* enc = half ? e_enc : u_enc;
    const float* s   = half ? col_sums : row_sums;

    int base = chunk * 32;
    float ev[32];
    #pragma unroll
    for (int j = 0; j < 32; ++j)
        ev[j] = enc[(size_t)(b * UDIM + base + j) * DDIM + d];
    #pragma unroll
    for (int j = 0; j < 32; ++j) KEEP(ev[j]);

    float acc = 0.f;
    #pragma unroll
    for (int j = 0; j < 32; ++j)
        acc += s[(size_t)b * UDIM + base + j] * ev[j];

    atomicAdd(&out[(size_t)b * 2 * DDIM + half * DDIM + d], acc);
}

// ---------------------------------------------------------------------------
extern "C" void kernel_launch(void* const* d_in, const int* in_sizes, int n_in,
                              void* d_out, int out_size, void* d_ws, size_t ws_size,
                              hipStream_t stream)
{
    const float* u_enc    = (const float*)d_in[0];
    const float* e_enc    = (const float*)d_in[1];
    const float* pair_enc = (const float*)d_in[2];
    const float* ue_mask  = (const float*)d_in[3];
    const float* w_kernel = (const float*)d_in[4];
    const float* w_bias   = (const float*)d_in[5];
    const float* bpp_w    = (const float*)d_in[6];
    const float* bpp_b    = (const float*)d_in[7];
    float* out = (float*)d_out;

    // ws layout: u_p bf16 (4MB) | e_p bf16 (4MB) | wT bf16 (128KB) | sums fp32 (64KB)
    ushort* u_p = (ushort*)d_ws;
    ushort* e_p = u_p + (size_t)BDIM * UDIM * PDIM;
    ushort* wT  = e_p + (size_t)BDIM * EDIM * PDIM;
    float* row_sums = (float*)(wT + (size_t)DDIM * PDIM);
    float* col_sums = row_sums + BDIM * UDIM;

    prep_kernel<<<dim3(64), 256, 0, stream>>>(w_kernel, wT, row_sums, out, out_size);

    proj_kernel<<<dim3(1024), 256, 0, stream>>>(u_enc, e_enc, wT, w_bias, u_p, e_p);

    fused_kernel<<<dim3(512), 256, 0, stream>>>(u_p, e_p, pair_enc, ue_mask,
                                                bpp_w, bpp_b, row_sums, col_sums);

    finish_kernel<<<dim3(BDIM, 2, 32), 256, 0, stream>>>(u_enc, e_enc, row_sums, col_sums, out);
}

// Round 7
// 148.622 us; speedup vs baseline: 1.0391x; 1.0391x over previous
//
#include <hip/hip_runtime.h>

// Problem constants (SubOut_60206851555968): B=8, U=E=1024, D=P=256, fp32 in/out.
#define BDIM 8
#define UDIM 1024
#define EDIM 1024
#define DDIM 256
#define PDIM 256

typedef __attribute__((ext_vector_type(8))) short bf16x8;   // 8 bf16 = 4 VGPRs
typedef __attribute__((ext_vector_type(4))) float f32x4;    // clang ext_vector: legal in asm "v"
typedef __attribute__((ext_vector_type(4))) ushort u16x4;

__device__ __forceinline__ short f2bf(float x) {
    unsigned u = __float_as_uint(x);
    unsigned r = (u + 0x7FFFu + ((u >> 16) & 1u)) >> 16;   // RNE
    return (short)r;
}

// Async global->LDS DMA, 16B per lane. LDS dest = wave-uniform base + lane*16;
// global src is per-lane (swizzled LDS layouts = pre-swizzle the SOURCE).
__device__ __forceinline__ void dma16(const void* g, void* lds) {
    __builtin_amdgcn_global_load_lds(
        (const __attribute__((address_space(1))) unsigned*)g,
        (__attribute__((address_space(3))) unsigned*)lds, 16, 0, 0);
}

// Keep-alive (ext_vector/scalar operands ONLY — HIP float4 is a class type).
#define KEEP(x) asm volatile("" :: "v"(x))

// ---------------------------------------------------------------------------
// prep: wT[n][k] = bf16(w[k][n]); zero out. Sums no longer need zeroing
// (v8: partial-sum slots each have exactly one non-atomic writer).
// ---------------------------------------------------------------------------
__global__ __launch_bounds__(256) void prep_kernel(
    const float* __restrict__ w, ushort* __restrict__ wT,
    float* __restrict__ out, int out_size)
{
    int k  = threadIdx.x;          // D index
    int n0 = blockIdx.x * 4;       // P index base
    f32x4 wv = *(const f32x4*)(w + (size_t)k * PDIM + n0);
    wT[(size_t)(n0 + 0) * DDIM + k] = (ushort)f2bf(wv[0]);
    wT[(size_t)(n0 + 1) * DDIM + k] = (ushort)f2bf(wv[1]);
    wT[(size_t)(n0 + 2) * DDIM + k] = (ushort)f2bf(wv[2]);
    wT[(size_t)(n0 + 3) * DDIM + k] = (ushort)f2bf(wv[3]);
    int g = blockIdx.x * 256 + k;
    if (g < out_size) out[g] = 0.f;
}

// ---------------------------------------------------------------------------
// proj v5: u_p/e_p = bf16(enc @ w + bias), MFMA 16x16x32 bf16.
// NEW (k-permutation store): op = sum_k u_p[u,k] e_p[e,k] is invariant under
// any k-permutation applied to BOTH u_p and e_p. Within each 64-col tile we
// store col (m*4 + nt) instead of (nt*16 + m): lane m's 4 outputs per row
// become CONTIGUOUS -> one ushort4 store per (quad,r) = 4 coalesced stores
// instead of 16 scattered 2B stores. fused reads identical positional
// k-slices on A and B (quad*8 + 32i), so the permutation cancels exactly.
// ---------------------------------------------------------------------------
__global__ __launch_bounds__(256) void proj_kernel(
    const float* __restrict__ u_enc, const float* __restrict__ e_enc,
    const ushort* __restrict__ wT, const float* __restrict__ bias,
    ushort* __restrict__ u_p, ushort* __restrict__ e_p)
{
    __shared__ ushort lds_b[64 * 256];   // 32 KB, swizzled: byte = rl*512 + (cb ^ ((rl&7)<<4))

    int bid  = blockIdx.x;                 // 0..1023
    int lin  = (bid & 7) * 128 + (bid >> 3);
    int row0 = (lin >> 2) * 64;
    int col0 = (lin & 3) * 64;

    const float* A; ushort* C;
    if (row0 < BDIM * UDIM) { A = u_enc; C = u_p; }
    else                    { A = e_enc; C = e_p; row0 -= BDIM * UDIM; }

    int tid  = threadIdx.x;
    int wave = tid >> 6, lane = tid & 63;
    int m = lane & 15, quad = lane >> 4;

    // ---- stage wT rows [col0, col0+64) into LDS, swizzled source ----
    {
        int rl_base = wave * 16;
        int lr = lane >> 5;            // 0/1
        int cb = (lane & 31) * 16;     // 0..496
        #pragma unroll
        for (int j = 0; j < 8; ++j) {
            int rl = rl_base + 2 * j + lr;
            const ushort* src = wT + (size_t)(col0 + rl) * DDIM + ((cb ^ ((rl & 7) << 4)) >> 1);
            dma16(src, &lds_b[(size_t)(rl_base + 2 * j) * DDIM]);
        }
    }

    // ---- A strip: 16 x f32x4 batched into registers, KEEP-pinned ----
    const float* aptr = A + (size_t)(row0 + wave * 16 + m) * DDIM + quad * 8;
    f32x4 a[16];
    #pragma unroll
    for (int i = 0; i < 8; ++i) {
        a[2 * i]     = *(const f32x4*)(aptr + 32 * i);
        a[2 * i + 1] = *(const f32x4*)(aptr + 32 * i + 4);
    }
    #pragma unroll
    for (int i = 0; i < 16; ++i) KEEP(a[i]);

    asm volatile("s_waitcnt vmcnt(0)" ::: "memory");
    __syncthreads();

    int rowmask = (m & 7) << 4;        // swizzle term: B row = nt*16 + m -> row&7 = m&7
    f32x4 acc[4] = {};
    #pragma unroll
    for (int i = 0; i < 8; ++i) {
        bf16x8 af;
        af[0] = f2bf(a[2*i][0]);   af[1] = f2bf(a[2*i][1]);
        af[2] = f2bf(a[2*i][2]);   af[3] = f2bf(a[2*i][3]);
        af[4] = f2bf(a[2*i+1][0]); af[5] = f2bf(a[2*i+1][1]);
        af[6] = f2bf(a[2*i+1][2]); af[7] = f2bf(a[2*i+1][3]);
        #pragma unroll
        for (int nt = 0; nt < 4; ++nt) {
            int elem = (nt * 16 + m) * DDIM + (((quad * 16 + 64 * i) ^ rowmask) >> 1);
            bf16x8 bfr = *(const bf16x8*)(lds_b + elem);
            acc[nt] = __builtin_amdgcn_mfma_f32_16x16x32_bf16(af, bfr, acc[nt], 0, 0, 0);
        }
    }

    // C/D layout: col = lane&15 (+16nt), row = quad*4 + reg.
    // Store k-permuted: tile-local col (m*4 + nt); one ushort4 per (quad,r).
    #pragma unroll
    for (int r = 0; r < 4; ++r) {
        int row = row0 + wave * 16 + quad * 4 + r;
        u16x4 pk;
        #pragma unroll
        for (int nt = 0; nt < 4; ++nt)
            pk[nt] = (ushort)f2bf(acc[nt][r] + bias[col0 + nt * 16 + m]);
        *(u16x4*)(C + (size_t)row * PDIM + col0 + 4 * m) = pk;
    }
}

// ---------------------------------------------------------------------------
// fused v8: op = u_p . e_p (MFMA), gate, row/col partial sums.
// Back to the v6b single-shot skeleton (the only structure that won: stage
// once to LDS, one drain, 65KB -> 2 blocks/CU; v7's deep pipeline was
// neutral at 1 block/CU). NEW: epilogue sums are NON-ATOMIC stores to
// disjoint partial slots (one writer per slot) — removes the atomic tail on
// every one of 2048 blocks, the cross-block contention, and the zero-init
// dependency on prep.
// ---------------------------------------------------------------------------
__global__ __launch_bounds__(256) void fused_kernel(
    const ushort* __restrict__ u_p, const ushort* __restrict__ e_p,
    const float* __restrict__ pair_enc, const float* __restrict__ ue_mask,
    const float* __restrict__ bpp_w_p, const float* __restrict__ bpp_b_p,
    float* __restrict__ row_part /*[B][16][1024]*/,
    float* __restrict__ col_part /*[B][16][1024]*/)
{
    __shared__ ushort lds_e[64 * 256];   // 32 KB, swizzled (same scheme as proj)
    __shared__ float lds_pair[64][64];   // 16 KB, linear
    __shared__ float lds_mask[64][64];   // 16 KB, linear
    __shared__ float colred[4][64];      // 1 KB

    int bid  = blockIdx.x;          // 0..2047
    int b    = bid & 7;             // batch <-> XCD (FETCH win, kept)
    int tile = bid >> 3;            // 0..255
    int iu = tile >> 4, ie = tile & 15;
    int u0 = iu * 64, e0 = ie * 64;

    int tid  = threadIdx.x;
    int wave = tid >> 6, lane = tid & 63;
    int m = lane & 15, quad = lane >> 4;

    const float* pm = pair_enc + (size_t)b * UDIM * EDIM;
    const float* mm = ue_mask  + (size_t)b * UDIM * EDIM;
    const ushort* eb = e_p + (size_t)b * EDIM * PDIM;

    // ---- stage e-tile rows [e0, e0+64) into swizzled LDS ----
    {
        int rl_base = wave * 16;
        int lr = lane >> 5;            // 0/1
        int cb = (lane & 31) * 16;     // byte-in-row 0..496
        #pragma unroll
        for (int j = 0; j < 8; ++j) {
            int rl = rl_base + 2 * j + lr;
            const ushort* src = eb + (size_t)(e0 + rl) * PDIM + ((cb ^ ((rl & 7) << 4)) >> 1);
            dma16(src, &lds_e[(size_t)(rl_base + 2 * j) * PDIM]);
        }
    }

    // ---- stage pair/mask tile rows owned by this wave (linear) ----
    {
        int lr = lane >> 4;            // 0..3
        int lc = (lane & 15) * 4;      // float col
        #pragma unroll
        for (int j = 0; j < 4; ++j) {
            int r0 = wave * 16 + j * 4;
            size_t goff = (size_t)(u0 + r0 + lr) * EDIM + e0 + lc;
            dma16(pm + goff, &lds_pair[r0][0]);
            dma16(mm + goff, &lds_mask[r0][0]);
        }
    }

    // ---- af frags: 8x16B batched into regs, KEEP-pinned, same drain ----
    const ushort* Au = u_p + (size_t)b * UDIM * PDIM + (size_t)(u0 + wave * 16 + m) * PDIM + quad * 8;
    bf16x8 af[8];
    #pragma unroll
    for (int i = 0; i < 8; ++i) af[i] = *(const bf16x8*)(Au + 32 * i);
    #pragma unroll
    for (int i = 0; i < 8; ++i) KEEP(af[i]);

    float bw = bpp_w_p[0], bb = bpp_b_p[0];

    asm volatile("s_waitcnt vmcnt(0)" ::: "memory");
    __syncthreads();

    // ---- MFMA loop, B frags from swizzled LDS ----
    int rowmask = (m & 7) << 4;
    f32x4 acc[4] = {};
    #pragma unroll
    for (int i = 0; i < 8; ++i) {
        #pragma unroll
        for (int nt = 0; nt < 4; ++nt) {
            int elem = (nt * 16 + m) * PDIM + (((quad * 16 + 64 * i) ^ rowmask) >> 1);
            bf16x8 bfr = *(const bf16x8*)(lds_e + elem);
            acc[nt] = __builtin_amdgcn_mfma_f32_16x16x32_bf16(af[i], bfr, acc[nt], 0, 0, 0);
        }
    }

    // ---- epilogue: gate + partial sums, all operands from LDS ----
    float rsum[4] = {0.f, 0.f, 0.f, 0.f};
    float csum[4] = {0.f, 0.f, 0.f, 0.f};
    #pragma unroll
    for (int r = 0; r < 4; ++r) {
        int row = wave * 16 + quad * 4 + r;
        #pragma unroll
        for (int nt = 0; nt < 4; ++nt) {
            int col = nt * 16 + m;
            float mv = lds_mask[row][col];
            float pv = lds_pair[row][col];
            float arg = bw * pv + bb + mv * acc[nt][r];
            float s = mv / (1.f + __expf(-arg));
            rsum[r]  += s;
            csum[nt] += s;
        }
    }

    // Row partials: quad-lane reduce; unique slot (b, ie, u) -> plain store.
    #pragma unroll
    for (int r = 0; r < 4; ++r) {
        float v = rsum[r];
        v += __shfl_xor(v, 1); v += __shfl_xor(v, 2);
        v += __shfl_xor(v, 4); v += __shfl_xor(v, 8);
        if (m == 0)
            row_part[((size_t)b * 16 + ie) * UDIM + u0 + wave * 16 + quad * 4 + r] = v;
    }

    // Col partials: reduce across quads, then across waves via LDS; unique
    // slot (b, iu, e) -> plain store.
    #pragma unroll
    for (int nt = 0; nt < 4; ++nt) {
        float v = csum[nt];
        v += __shfl_xor(v, 16); v += __shfl_xor(v, 32);
        if (quad == 0) colred[wave][nt * 16 + m] = v;
    }
    __syncthreads();

    if (tid < 64) {
        float v = colred[0][tid] + colred[1][tid] + colred[2][tid] + colred[3][tid];
        col_part[((size_t)b * 16 + iu) * EDIM + e0 + tid] = v;
    }
}

// ---------------------------------------------------------------------------
// finish v4: out[b,0:256] = (sum_p row_part[b][p]) @ u_enc[b];
//            out[b,256:512] = (sum_p col_part[b][p]) @ e_enc[b].
// Phase 1: 32 threads sum the 16 partials per row (indices thread-uniform ->
// scalar loads) into LDS. Phase 2: 32-deep KEEP-pinned MAC as before.
// ---------------------------------------------------------------------------
__global__ __launch_bounds__(256) void finish_kernel(
    const float* __restrict__ u_enc, const float* __restrict__ e_enc,
    const float* __restrict__ row_part, const float* __restrict__ col_part,
    float* __restrict__ out)
{
    __shared__ float s_lds[32];

    int b = blockIdx.x;
    int half = blockIdx.y;
    int chunk = blockIdx.z;        // 0..31
    int d = threadIdx.x;

    const float* enc  = half ? e_enc   : u_enc;
    const float* part = half ? col_part : row_part;

    int base = chunk * 32;
    if (d < 32) {
        float s = 0.f;
        #pragma unroll
        for (int p = 0; p < 16; ++p)
            s += part[((size_t)b * 16 + p) * UDIM + base + d];
        s_lds[d] = s;
    }

    float ev[32];
    #pragma unroll
    for (int j = 0; j < 32; ++j)
        ev[j] = enc[(size_t)(b * UDIM + base + j) * DDIM + d];
    #pragma unroll
    for (int j = 0; j < 32; ++j) KEEP(ev[j]);

    __syncthreads();

    float acc = 0.f;
    #pragma unroll
    for (int j = 0; j < 32; ++j)
        acc += s_lds[j] * ev[j];

    atomicAdd(&out[(size_t)b * 2 * DDIM + half * DDIM + d], acc);
}

// ---------------------------------------------------------------------------
extern "C" void kernel_launch(void* const* d_in, const int* in_sizes, int n_in,
                              void* d_out, int out_size, void* d_ws, size_t ws_size,
                              hipStream_t stream)
{
    const float* u_enc    = (const float*)d_in[0];
    const float* e_enc    = (const float*)d_in[1];
    const float* pair_enc = (const float*)d_in[2];
    const float* ue_mask  = (const float*)d_in[3];
    const float* w_kernel = (const float*)d_in[4];
    const float* w_bias   = (const float*)d_in[5];
    const float* bpp_w    = (const float*)d_in[6];
    const float* bpp_b    = (const float*)d_in[7];
    float* out = (float*)d_out;

    // ws layout: u_p bf16 (4MB) | e_p bf16 (4MB) | wT bf16 (128KB) |
    //            row_part fp32 (512KB) | col_part fp32 (512KB)
    ushort* u_p = (ushort*)d_ws;
    ushort* e_p = u_p + (size_t)BDIM * UDIM * PDIM;
    ushort* wT  = e_p + (size_t)BDIM * EDIM * PDIM;
    float* row_part = (float*)(wT + (size_t)DDIM * PDIM);
    float* col_part = row_part + (size_t)BDIM * 16 * UDIM;

    prep_kernel<<<dim3(64), 256, 0, stream>>>(w_kernel, wT, out, out_size);

    proj_kernel<<<dim3(1024), 256, 0, stream>>>(u_enc, e_enc, wT, w_bias, u_p, e_p);

    fused_kernel<<<dim3(2048), 256, 0, stream>>>(u_p, e_p, pair_enc, ue_mask,
                                                 bpp_w, bpp_b, row_part, col_part);

    finish_kernel<<<dim3(BDIM, 2, 32), 256, 0, stream>>>(u_enc, e_enc, row_part, col_part, out);
}